// Round 2
// baseline (1082.585 us; speedup 1.0000x reference)
//
#include <hip/hip_runtime.h>
#include <hip/hip_bf16.h>

#define SEQ   128
#define BATCH 256
#define HID   1024
#define DIM   1024

typedef float f32x4 __attribute__((ext_vector_type(4)));
typedef short s16x8 __attribute__((ext_vector_type(8)));

__device__ __forceinline__ unsigned short f2bf(float x) {
    __hip_bfloat16 h = __float2bfloat16(x);
    unsigned short u;
    __builtin_memcpy(&u, &h, 2);
    return u;
}
__device__ __forceinline__ unsigned int bf16pair(float lo, float hi) {
    return (unsigned int)f2bf(lo) | ((unsigned int)f2bf(hi) << 16);
}
__device__ __forceinline__ float blo(unsigned int u) { return __uint_as_float(u << 16); }
__device__ __forceinline__ float bhi(unsigned int u) { return __uint_as_float(u & 0xFFFF0000u); }

// ---------------------------------------------------------------------------
// K0: Q = topic @ Wq + bq   (fp32, 256x1024x1024 — tiny)
// ---------------------------------------------------------------------------
__global__ __launch_bounds__(256)
void k_q(const float* __restrict__ topic, const float* __restrict__ Wq,
         const float* __restrict__ bq, float* __restrict__ Q)
{
    __shared__ float AsT[32][34];
    __shared__ float Bs[32][34];
    const int t  = threadIdx.x;
    const int b0 = blockIdx.y * 32, d0 = blockIdx.x * 32;
    const int tx = t & 15, ty = t >> 4;
    float acc[2][2] = {{0.f, 0.f}, {0.f, 0.f}};

    for (int kt = 0; kt < 32; ++kt) {
#pragma unroll
        for (int i = 0; i < 4; ++i) {
            int id = t + 256 * i;          // 0..1023
            int r  = id >> 5, c = id & 31; // r: row-of-32, c: col-of-32
            AsT[c][r] = topic[(size_t)(b0 + r) * HID + kt * 32 + c]; // transposed
            Bs[r][c]  = Wq[(size_t)(kt * 32 + r) * DIM + d0 + c];
        }
        __syncthreads();
#pragma unroll
        for (int kk = 0; kk < 32; ++kk) {
            float a0 = AsT[kk][ty * 2], a1 = AsT[kk][ty * 2 + 1];
            float w0 = Bs[kk][tx * 2],  w1 = Bs[kk][tx * 2 + 1];
            acc[0][0] += a0 * w0; acc[0][1] += a0 * w1;
            acc[1][0] += a1 * w0; acc[1][1] += a1 * w1;
        }
        __syncthreads();
    }
#pragma unroll
    for (int i = 0; i < 2; ++i)
#pragma unroll
        for (int j = 0; j < 2; ++j)
            Q[(size_t)(b0 + ty * 2 + i) * DIM + d0 + tx * 2 + j] =
                acc[i][j] + bq[d0 + tx * 2 + j];
}

// ---------------------------------------------------------------------------
// K1: main fused GEMM.
//   Block: s = blockIdx.z, b-range = blockIdx.y*64 .. +63, d-range = blockIdx.x*128 .. +127
//   A tile rows (128): 16-row chunks alternate topic/text so V0/V1 of the same b
//   live in m-frags (2i, 2i+1) of the same wave -> lane-local packing.
//   LDS: As / Bs each as two 32-k halves of [128 rows][32 k] bf16 (row = 64 B).
//   Bs has 16B-chunk XOR swizzle: phys_chunk = chunk ^ ((n>>1)&3).
// ---------------------------------------------------------------------------
__global__ __launch_bounds__(256, 2)
void k_main(const float* __restrict__ topic, const float* __restrict__ text,
            const float* __restrict__ Wv, const float* __restrict__ bv,
            const float* __restrict__ Q,
            float* __restrict__ s0g, float* __restrict__ s1g,
            unsigned int* __restrict__ outp)
{
    __shared__ uint4 smemv[2048];      // 32 KB: A in [0,16K), B in [16K,32K)
    char* smem = (char*)smemv;

    const int tid = threadIdx.x;
    const int l   = tid & 63;
    const int w   = __builtin_amdgcn_readfirstlane(tid >> 6);
    const int s   = blockIdx.z;
    const int b0  = blockIdx.y * 64;
    const int n0  = blockIdx.x * 128;

    const float* textS = text + (size_t)s * BATCH * HID;
    const float* WvS   = Wv + (size_t)s * HID * DIM;

    // ---- A staging assignment: thread covers rows w*32 + (l>>3) + 8j, 8-k chunk c8=l&7
    const int l3 = l >> 3;
    const int c8 = l & 7;
    const float* rowp[4];
    int aWoff[4];
#pragma unroll
    for (int j = 0; j < 4; ++j) {
        int r = w * 32 + l3 + 8 * j;
        int q = r >> 4;
        int b = b0 + (q >> 1) * 16 + (r & 15);
        const float* base = (q & 1) ? textS : topic;
        rowp[j]  = base + (size_t)b * HID + c8 * 8;
        aWoff[j] = (c8 >> 2) * 8192 + r * 64 + (c8 & 3) * 16;
    }

    // ---- B staging: wave w covers k = w*16..w*16+15 (within BK=64), n = l and l+64
    const float* bptr = WvS + (size_t)(w * 16) * DIM + n0;
    const int fB = (l >> 1) & 3;
    int bWoff[2][2];
#pragma unroll
    for (int nn = 0; nn < 2; ++nn)
#pragma unroll
        for (int cc = 0; cc < 2; ++cc) {
            int n  = l + nn * 64;
            int c  = (w & 1) * 2 + cc;
            bWoff[nn][cc] = 16384 + (w >> 1) * 8192 + n * 64 + (c ^ fB) * 16;
        }

    // ---- fragment read constants
    const int l15 = l & 15, l4 = l >> 4;
    const int fRead = (l15 >> 1) & 3;
    const int Mw = (w >> 1) * 64, Nw = (w & 1) * 64;

    f32x4 acc[4][4];
#pragma unroll
    for (int i = 0; i < 4; ++i)
#pragma unroll
        for (int j = 0; j < 4; ++j) acc[i][j] = f32x4{0.f, 0.f, 0.f, 0.f};

    // ---- prefetch tile 0
    float4 aReg[4][2];
    float  bReg[16][2];
#pragma unroll
    for (int j = 0; j < 4; ++j) {
        aReg[j][0] = ((const float4*)rowp[j])[0];
        aReg[j][1] = ((const float4*)rowp[j])[1];
    }
    {
        const float* p = bptr;
#pragma unroll
        for (int kk = 0; kk < 16; ++kk) {
            bReg[kk][0] = p[l];
            bReg[kk][1] = p[l + 64];
            p += DIM;
        }
    }

    for (int kt = 0; kt < 16; ++kt) {
        // convert + write LDS (current tile)
#pragma unroll
        for (int j = 0; j < 4; ++j) {
            uint4 u;
            u.x = bf16pair(aReg[j][0].x, aReg[j][0].y);
            u.y = bf16pair(aReg[j][0].z, aReg[j][0].w);
            u.z = bf16pair(aReg[j][1].x, aReg[j][1].y);
            u.w = bf16pair(aReg[j][1].z, aReg[j][1].w);
            *(uint4*)(smem + aWoff[j]) = u;
        }
#pragma unroll
        for (int nn = 0; nn < 2; ++nn)
#pragma unroll
            for (int cc = 0; cc < 2; ++cc) {
                int k0 = cc * 8;
                uint4 u;
                u.x = bf16pair(bReg[k0 + 0][nn], bReg[k0 + 1][nn]);
                u.y = bf16pair(bReg[k0 + 2][nn], bReg[k0 + 3][nn]);
                u.z = bf16pair(bReg[k0 + 4][nn], bReg[k0 + 5][nn]);
                u.w = bf16pair(bReg[k0 + 6][nn], bReg[k0 + 7][nn]);
                *(uint4*)(smem + bWoff[nn][cc]) = u;
            }
        __syncthreads();

        // prefetch next tile while MFMAs run
        if (kt < 15) {
#pragma unroll
            for (int j = 0; j < 4; ++j) {
                rowp[j] += 64;
                aReg[j][0] = ((const float4*)rowp[j])[0];
                aReg[j][1] = ((const float4*)rowp[j])[1];
            }
            bptr += 64 * DIM;
            const float* p = bptr;
#pragma unroll
            for (int kk = 0; kk < 16; ++kk) {
                bReg[kk][0] = p[l];
                bReg[kk][1] = p[l + 64];
                p += DIM;
            }
        }

        // compute
#pragma unroll
        for (int ks = 0; ks < 2; ++ks) {
            s16x8 aF[4], bF[4];
#pragma unroll
            for (int i = 0; i < 4; ++i)
                aF[i] = *(const s16x8*)(smem + ks * 8192 + (Mw + i * 16 + l15) * 64 + l4 * 16);
#pragma unroll
            for (int i = 0; i < 4; ++i)
                bF[i] = *(const s16x8*)(smem + 16384 + ks * 8192 + (Nw + i * 16 + l15) * 64 +
                                        ((l4 ^ fRead) * 16));
#pragma unroll
            for (int i = 0; i < 4; ++i)
#pragma unroll
                for (int j = 0; j < 4; ++j)
                    acc[i][j] = __builtin_amdgcn_mfma_f32_16x16x32_bf16(aF[i], bF[j], acc[i][j], 0, 0, 0);
        }
        __syncthreads();
    }

    // ---- epilogue: bias, Q-dots, packed V store, atomic logits
    float bvv[4];
#pragma unroll
    for (int i = 0; i < 4; ++i)
        bvv[i] = bv[s * DIM + n0 + Nw + i * 16 + l15];

#pragma unroll
    for (int ip = 0; ip < 4; ip += 2) {          // (V0 frag, V1 frag) pairs
#pragma unroll
        for (int j = 0; j < 4; ++j) {
            int r0 = Mw + ip * 16 + l4 * 4 + j;  // V0 row
            int b  = b0 + (r0 >> 5) * 16 + (r0 & 15);
            const float* Qrow = Q + (size_t)b * DIM + n0 + Nw + l15;
            float d0 = 0.f, d1 = 0.f;
            float v0s[4], v1s[4];
#pragma unroll
            for (int in_ = 0; in_ < 4; ++in_) {
                float v0 = acc[ip][in_][j] + bvv[in_];
                float v1 = acc[ip + 1][in_][j] + bvv[in_];
                float qv = Qrow[in_ * 16];
                d0 += qv * v0;
                d1 += qv * v1;
                v0s[in_] = v0; v1s[in_] = v1;
            }
            unsigned int* orow = outp + ((size_t)(s * BATCH + b)) * DIM + n0 + Nw + l15;
#pragma unroll
            for (int in_ = 0; in_ < 4; ++in_)
                orow[in_ * 16] = bf16pair(v0s[in_], v1s[in_]);   // lo=V0, hi=V1
#pragma unroll
            for (int m = 1; m < 16; m <<= 1) {
                d0 += __shfl_xor(d0, m, 64);
                d1 += __shfl_xor(d1, m, 64);
            }
            if (l15 == 0) {
                atomicAdd(&s0g[s * BATCH + b], d0);
                atomicAdd(&s1g[s * BATCH + b], d1);
            }
        }
    }
}

// ---------------------------------------------------------------------------
// K2: 2-way softmax + recombine, in place on d_out.
// ---------------------------------------------------------------------------
__global__ __launch_bounds__(256)
void k_combine(const float* __restrict__ s0g, const float* __restrict__ s1g,
               float* __restrict__ outf)
{
    const int row = blockIdx.x;                 // s*BATCH + b
    const float scale = 0.03125f;               // 1/sqrt(1024)
    float s0 = s0g[row] * scale;
    float s1 = s1g[row] * scale;
    float e  = __expf(s1 - s0);
    float a0 = 1.f / (1.f + e);
    float a1 = e / (1.f + e);
    float* p = outf + (size_t)row * DIM + threadIdx.x * 4;
    uint4 u = *(const uint4*)p;
    float4 o;
    o.x = a0 * blo(u.x) + a1 * bhi(u.x);
    o.y = a0 * blo(u.y) + a1 * bhi(u.y);
    o.z = a0 * blo(u.z) + a1 * bhi(u.z);
    o.w = a0 * blo(u.w) + a1 * bhi(u.w);
    *(float4*)p = o;
}

// ---------------------------------------------------------------------------
extern "C" void kernel_launch(void* const* d_in, const int* in_sizes, int n_in,
                              void* d_out, int out_size, void* d_ws, size_t ws_size,
                              hipStream_t stream)
{
    (void)in_sizes; (void)n_in; (void)out_size; (void)ws_size;
    const float* topic = (const float*)d_in[0];
    const float* text  = (const float*)d_in[1];
    const float* Wq    = (const float*)d_in[2];
    const float* bq    = (const float*)d_in[3];
    const float* Wv    = (const float*)d_in[4];
    const float* bv    = (const float*)d_in[5];

    float* Q  = (float*)d_ws;                                  // 1 MB
    float* s0 = (float*)((char*)d_ws + (1 << 20));             // 128 KB
    float* s1 = s0 + SEQ * BATCH;                              // 128 KB

    (void)hipMemsetAsync(s0, 0, 2 * SEQ * BATCH * sizeof(float), stream);
    k_q<<<dim3(32, 8), 256, 0, stream>>>(topic, Wq, bq, Q);
    k_main<<<dim3(8, 4, SEQ), 256, 0, stream>>>(topic, text, Wv, bv, Q, s0, s1,
                                                (unsigned int*)d_out);
    k_combine<<<SEQ * BATCH, 256, 0, stream>>>(s0, s1, (float*)d_out);
}